// Round 1
// baseline (208.693 us; speedup 1.0000x reference)
//
#include <hip/hip_runtime.h>

#define BB 64
#define LCC 512
#define LQQ 64
#define DDD 256

typedef short bf16x8 __attribute__((ext_vector_type(8)));
typedef float f32x4 __attribute__((ext_vector_type(4)));

static __device__ __forceinline__ unsigned short f2bf(float f) {
  union { float f; unsigned u; } v; v.f = f;
  unsigned u = v.u;
  return (unsigned short)((u + 0x7fffu + ((u >> 16) & 1u)) >> 16);
}

static __device__ __forceinline__ void nt_store4(float* p, float a, float b, float c, float d) {
  f32x4 v = { a, b, c, d };
  __builtin_nontemporal_store(v, (f32x4*)p);
}

// ---------------------------------------------------------------------------
// Kernel 1: E = exp((cx*wi)@qu^T + s_c + s_q + bias); writes
//   P  = diag(1/rowsum) * E   (bf16, for k3's A and Bm)
//   Et = E^T                  (bf16, for k2's T)
//   csp[b][tile][64]          (f32 per-tile column-sum partials, for k2)
//   out[:, :, 0:256] = contex (streamed from the K-loop registers)
// grid 512 = B x 8 LC-tiles of 64; 256 threads (4 waves).
// ---------------------------------------------------------------------------
__global__ __launch_bounds__(256) void k1_scores(
    const float* __restrict__ cx, const float* __restrict__ qu,
    const float* __restrict__ W, const float* __restrict__ Wb,
    unsigned short* __restrict__ P, unsigned short* __restrict__ Et,
    float* __restrict__ csp, float* __restrict__ out)
{
  __shared__ float w_lds[768];                 // wq | wc | wi
  __shared__ unsigned short Bs[64 * 264];      // qu tile bf16, full K, +8 pad
  __shared__ float E_lds[64 * 65];
  __shared__ float red[256];
  __shared__ float sc_lds[64];
  __shared__ float sq_lds[64];
  __shared__ float ri_s[64];

  const int tid = threadIdx.x;
  const int b    = blockIdx.x >> 3;
  const int tile = blockIdx.x & 7;
  const int i0 = tile * 64;
  const int w = tid >> 6, lane = tid & 63, quad = lane >> 4, ln = lane & 15;

  for (int idx = tid; idx < 768; idx += 256) w_lds[idx] = W[idx];
  __syncthreads();

  // stage Bs = qu (bf16, 64 x 256), fold s_q partials
  {
    const int bj = tid >> 2, bc = tid & 3;
    const float4* src = (const float4*)(qu + ((size_t)(b * LQQ + bj)) * DDD + bc * 64);
    const float* wq = w_lds + bc * 64;
    unsigned short* dst = Bs + bj * 264 + bc * 64;
    float sqp = 0.f;
#pragma unroll
    for (int u = 0; u < 16; ++u) {
      float4 v = src[u];
      sqp += v.x * wq[u*4+0] + v.y * wq[u*4+1] + v.z * wq[u*4+2] + v.w * wq[u*4+3];
      ushort4 o = { f2bf(v.x), f2bf(v.y), f2bf(v.z), f2bf(v.w) };
      *(ushort4*)(dst + u * 4) = o;
    }
    red[tid] = sqp;
  }
  __syncthreads();
  if (tid < 64) sq_lds[tid] = red[4*tid] + red[4*tid+1] + red[4*tid+2] + red[4*tid+3];

  f32x4 acc[4];
#pragma unroll
  for (int c = 0; c < 4; ++c) acc[c] = (f32x4){0.f, 0.f, 0.f, 0.f};

  // K loop: no barriers. A fragment = cx row (w*16+ln), k-slice quad*8.
  // Also streams the contex copy into out[:, :, 0:256].
  float scp = 0.f;
  const float* cxrow = cx + ((size_t)(b * LCC + i0 + w * 16 + ln)) * DDD;
  float* outrow = out + ((size_t)(b * LCC + i0 + w * 16 + ln)) * 1024;
#pragma unroll
  for (int kk = 0; kk < 4; ++kk)
#pragma unroll
    for (int ks = 0; ks < 2; ++ks) {
      const int k0 = kk * 64 + ks * 32 + quad * 8;
      float4 c0 = *(const float4*)(cxrow + k0);
      float4 c1 = *(const float4*)(cxrow + k0 + 4);
      nt_store4(outrow + k0,     c0.x, c0.y, c0.z, c0.w);
      nt_store4(outrow + k0 + 4, c1.x, c1.y, c1.z, c1.w);
      const float* wcp = w_lds + 256 + k0;
      const float* wip = w_lds + 512 + k0;
      scp += c0.x*wcp[0] + c0.y*wcp[1] + c0.z*wcp[2] + c0.w*wcp[3]
           + c1.x*wcp[4] + c1.y*wcp[5] + c1.z*wcp[6] + c1.w*wcp[7];
      bf16x8 af;
      af[0] = (short)f2bf(c0.x * wip[0]);
      af[1] = (short)f2bf(c0.y * wip[1]);
      af[2] = (short)f2bf(c0.z * wip[2]);
      af[3] = (short)f2bf(c0.w * wip[3]);
      af[4] = (short)f2bf(c1.x * wip[4]);
      af[5] = (short)f2bf(c1.y * wip[5]);
      af[6] = (short)f2bf(c1.z * wip[6]);
      af[7] = (short)f2bf(c1.w * wip[7]);
#pragma unroll
      for (int tn = 0; tn < 4; ++tn) {
        bf16x8 bf = *(const bf16x8*)(Bs + (tn * 16 + ln) * 264 + k0);
        acc[tn] = __builtin_amdgcn_mfma_f32_16x16x32_bf16(af, bf, acc[tn], 0, 0, 0);
      }
    }

  // reduce s_c (4 quad-partials per row), add bias
  __syncthreads();
  red[(w * 16 + ln) * 4 + quad] = scp;
  __syncthreads();
  if (tid < 64)
    sc_lds[tid] = red[4*tid] + red[4*tid+1] + red[4*tid+2] + red[4*tid+3] + Wb[0];
  __syncthreads();

  // exp epilogue into E_lds (C/D layout: col=lane&15, row=quad*4+r)
#pragma unroll
  for (int tn = 0; tn < 4; ++tn)
#pragma unroll
    for (int r = 0; r < 4; ++r) {
      int il = w * 16 + quad * 4 + r;
      int j  = tn * 16 + ln;
      E_lds[il * 65 + j] = __expf(acc[tn][r] + sc_lds[il] + sq_lds[j]);
    }
  __syncthreads();
  // rowsum (4 threads/row) -> ri_s
  {
    const int i = tid >> 2, c = tid & 3;
    float s = 0.f;
#pragma unroll
    for (int j = 0; j < 16; ++j) s += E_lds[i * 65 + c * 16 + j];
    red[tid] = s;
  }
  __syncthreads();
  if (tid < 64)
    ri_s[tid] = 1.0f / (red[4*tid] + red[4*tid+1] + red[4*tid+2] + red[4*tid+3]);
  __syncthreads();
  // colsum partials (f32, unscaled E) -> csp
  {
    const int j = tid >> 2, c = tid & 3;
    float s = 0.f;
#pragma unroll
    for (int r = 0; r < 16; ++r) s += E_lds[(c * 16 + r) * 65 + j];
    red[tid] = s;
  }
  __syncthreads();
  if (tid < 64)
    csp[((size_t)(b * 8 + tile)) * 64 + tid] =
        red[4*tid] + red[4*tid+1] + red[4*tid+2] + red[4*tid+3];

  // write P = diag(1/rowsum)*E, natural (B, 512, 64) bf16
  {
    const int i = tid >> 2, c = tid & 3;
    const float ri = ri_s[i];
    unsigned short* dst = P + ((size_t)(b * LCC + i0 + i)) * 64 + c * 16;
    const float* srcr = E_lds + i * 65 + c * 16;
#pragma unroll
    for (int u = 0; u < 4; ++u) {
      ushort4 o = { f2bf(srcr[u*4+0]*ri), f2bf(srcr[u*4+1]*ri),
                    f2bf(srcr[u*4+2]*ri), f2bf(srcr[u*4+3]*ri) };
      *(ushort4*)(dst + u * 4) = o;
    }
  }
  // write E^T (B, 64, 512) bf16 (unscaled — k2 applies colsum scaling)
  {
    const int j = tid >> 2, c = tid & 3;
    unsigned short* dst = Et + ((size_t)(b * LQQ + j)) * LCC + i0 + c * 16;
#pragma unroll
    for (int u = 0; u < 4; ++u) {
      ushort4 o;
      o.x = f2bf(E_lds[(c*16 + u*4 + 0) * 65 + j]);
      o.y = f2bf(E_lds[(c*16 + u*4 + 1) * 65 + j]);
      o.z = f2bf(E_lds[(c*16 + u*4 + 2) * 65 + j]);
      o.w = f2bf(E_lds[(c*16 + u*4 + 3) * 65 + j]);
      *(ushort4*)(dst + u * 4) = o;
    }
  }
}

// ---------------------------------------------------------------------------
// Kernel 2: T = diag(1/colsum) * E^T @ contex -> T^T (bf16); also Q^T (bf16)
// colsum comes precomputed (f32 partials from k1). Staging loads remapped
// to 128B-contiguous per-row segments. grid 512 = B x 8 D-slices of 32.
// ---------------------------------------------------------------------------
__global__ __launch_bounds__(256) void k2_tmat(
    const float* __restrict__ cx, const float* __restrict__ qu,
    const unsigned short* __restrict__ Et, const float* __restrict__ csp,
    unsigned short* __restrict__ Qt, unsigned short* __restrict__ Tt)
{
  __shared__ unsigned short Bs2[32 * 72];
  __shared__ float Tl[64 * 37];
  __shared__ float csinv[64];

  const int tid = threadIdx.x;
  const int b  = blockIdx.x >> 3;
  const int d0 = (blockIdx.x & 7) * 32;
  const int w = tid >> 6, lane = tid & 63, quad = lane >> 4, ln = lane & 15;

  // ---- transpose question slice -> Qt ----
  {
    const int j = tid >> 2, c = tid & 3;
    const float* srow = qu + ((size_t)(b * LQQ + j)) * DDD + d0 + c * 8;
    float4 v0 = *(const float4*)srow;
    float4 v1 = *(const float4*)(srow + 4);
    float* t = Tl + j * 37 + c * 8;
    t[0]=v0.x; t[1]=v0.y; t[2]=v0.z; t[3]=v0.w;
    t[4]=v1.x; t[5]=v1.y; t[6]=v1.z; t[7]=v1.w;
  }
  __syncthreads();
  {
    const int d = tid >> 3, cj = tid & 7;
    unsigned short* dst = Qt + ((size_t)(b * DDD + d0 + d)) * 64 + cj * 8;
    ushort4 o0 = { f2bf(Tl[(cj*8+0)*37+d]), f2bf(Tl[(cj*8+1)*37+d]),
                   f2bf(Tl[(cj*8+2)*37+d]), f2bf(Tl[(cj*8+3)*37+d]) };
    ushort4 o1 = { f2bf(Tl[(cj*8+4)*37+d]), f2bf(Tl[(cj*8+5)*37+d]),
                   f2bf(Tl[(cj*8+6)*37+d]), f2bf(Tl[(cj*8+7)*37+d]) };
    *(ushort4*)dst = o0;
    *(ushort4*)(dst + 4) = o1;
  }

  // exact colsum inverse from k1's f32 partials
  if (tid < 64) {
    float s = 0.f;
#pragma unroll
    for (int t = 0; t < 8; ++t) s += csp[((size_t)(b * 8 + t)) * 64 + tid];
    csinv[tid] = 1.0f / s;
  }

  f32x4 acc[2];
  acc[0] = (f32x4){0.f, 0.f, 0.f, 0.f};
  acc[1] = (f32x4){0.f, 0.f, 0.f, 0.f};
  const unsigned short* etrow = Et + ((size_t)(b * LQQ + w * 16 + ln)) * LCC;
  const int r2 = tid >> 2, c2 = tid & 3;

  for (int kk = 0; kk < 8; ++kk) {
    __syncthreads();   // previous Bs2 reads done (also fences Qt-phase Tl reads at kk=0)
    // stage Bs2[d][i] = contex[k0+i][d0+d] (bf16 transposed)
    // remapped: thread owns row r2, 8-col chunk c2 -> 128B contiguous loads/row
    {
      const float* srow = cx + ((size_t)(b * LCC + kk * 64 + r2)) * DDD + d0 + c2 * 8;
      float4 v0 = *(const float4*)srow;
      float4 v1 = *(const float4*)(srow + 4);
      Bs2[(c2*8+0)*72 + r2] = f2bf(v0.x);
      Bs2[(c2*8+1)*72 + r2] = f2bf(v0.y);
      Bs2[(c2*8+2)*72 + r2] = f2bf(v0.z);
      Bs2[(c2*8+3)*72 + r2] = f2bf(v0.w);
      Bs2[(c2*8+4)*72 + r2] = f2bf(v1.x);
      Bs2[(c2*8+5)*72 + r2] = f2bf(v1.y);
      Bs2[(c2*8+6)*72 + r2] = f2bf(v1.z);
      Bs2[(c2*8+7)*72 + r2] = f2bf(v1.w);
    }
    // direct-global A fragments
    bf16x8 af0 = *(const bf16x8*)(etrow + kk * 64 + quad * 8);
    bf16x8 af1 = *(const bf16x8*)(etrow + kk * 64 + 32 + quad * 8);
    __syncthreads();
#pragma unroll
    for (int tn = 0; tn < 2; ++tn) {
      bf16x8 bf0 = *(const bf16x8*)(Bs2 + (tn * 16 + ln) * 72 + quad * 8);
      bf16x8 bf1 = *(const bf16x8*)(Bs2 + (tn * 16 + ln) * 72 + 32 + quad * 8);
      acc[tn] = __builtin_amdgcn_mfma_f32_16x16x32_bf16(af0, bf0, acc[tn], 0, 0, 0);
      acc[tn] = __builtin_amdgcn_mfma_f32_16x16x32_bf16(af1, bf1, acc[tn], 0, 0, 0);
    }
  }

  // park T (scaled) into Tl
#pragma unroll
  for (int tn = 0; tn < 2; ++tn)
#pragma unroll
    for (int r = 0; r < 4; ++r) {
      int j = w * 16 + quad * 4 + r;
      Tl[j * 37 + tn * 16 + ln] = acc[tn][r] * csinv[j];
    }
  __syncthreads();
  // write T^T (B, 256, 64) bf16
  {
    const int d = tid >> 3, cj = tid & 7;
    unsigned short* dst = Tt + ((size_t)(b * DDD + d0 + d)) * 64 + cj * 8;
    ushort4 o0 = { f2bf(Tl[(cj*8+0)*37+d]), f2bf(Tl[(cj*8+1)*37+d]),
                   f2bf(Tl[(cj*8+2)*37+d]), f2bf(Tl[(cj*8+3)*37+d]) };
    ushort4 o1 = { f2bf(Tl[(cj*8+4)*37+d]), f2bf(Tl[(cj*8+5)*37+d]),
                   f2bf(Tl[(cj*8+6)*37+d]), f2bf(Tl[(cj*8+7)*37+d]) };
    *(ushort4*)dst = o0;
    *(ushort4*)(dst + 4) = o1;
  }
}

// ---------------------------------------------------------------------------
// Kernel 3: A = P @ qu, Bm = P @ T  (P already rowsum-scaled). One block per
// 64-row tile computes BOTH products; reads P and cx once; writes
// out[:,:,256:1024] = [A | cx*A | cx*Bm]. grid 512 = B x 8.
// ---------------------------------------------------------------------------
__global__ __launch_bounds__(256, 2) void k3_out(
    const float* __restrict__ cx,
    const unsigned short* __restrict__ P,
    const unsigned short* __restrict__ Qt,
    const unsigned short* __restrict__ Tt,
    float* __restrict__ out)
{
  __shared__ float TrA[16 * 260];
  __shared__ float TrB[16 * 260];

  const int tid = threadIdx.x;
  const int b  = blockIdx.x >> 3;
  const int i0 = (blockIdx.x & 7) * 64;
  const int w = tid >> 6, lane = tid & 63, quad = lane >> 4, ln = lane & 15;

  const unsigned short* pbase = P + ((size_t)(b * LCC + i0)) * 64;
  const unsigned short* qbase = Qt + (size_t)b * DDD * 64;
  const unsigned short* tbase = Tt + (size_t)b * DDD * 64;

  f32x4 accA[4][4], accB[4][4];
#pragma unroll
  for (int a = 0; a < 4; ++a)
#pragma unroll
    for (int c = 0; c < 4; ++c) {
      accA[a][c] = (f32x4){0.f, 0.f, 0.f, 0.f};
      accB[a][c] = (f32x4){0.f, 0.f, 0.f, 0.f};
    }

#pragma unroll
  for (int ks = 0; ks < 2; ++ks) {
    bf16x8 af[4];
#pragma unroll
    for (int tm = 0; tm < 4; ++tm)
      af[tm] = *(const bf16x8*)(pbase + (tm * 16 + ln) * 64 + ks * 32 + quad * 8);
#pragma unroll
    for (int tn = 0; tn < 4; ++tn) {
      const size_t boff = ((size_t)(w * 64 + tn * 16 + ln)) * 64 + ks * 32 + quad * 8;
      bf16x8 bq = *(const bf16x8*)(qbase + boff);
      bf16x8 bt = *(const bf16x8*)(tbase + boff);
#pragma unroll
      for (int tm = 0; tm < 4; ++tm) {
        accA[tm][tn] = __builtin_amdgcn_mfma_f32_16x16x32_bf16(af[tm], bq, accA[tm][tn], 0, 0, 0);
        accB[tm][tn] = __builtin_amdgcn_mfma_f32_16x16x32_bf16(af[tm], bt, accB[tm][tn], 0, 0, 0);
      }
    }
  }

  const float* cxb = cx + (size_t)b * LCC * DDD;
  float* ob = out + (size_t)b * LCC * 1024;
  const int row = tid >> 4;   // 0..15
  const int fq  = tid & 15;

#pragma unroll
  for (int tm = 0; tm < 4; ++tm) {
    // park 16 rows x 256 cols of A and Bm (C/D-layout -> row-major)
#pragma unroll
    for (int tn = 0; tn < 4; ++tn)
#pragma unroll
      for (int r = 0; r < 4; ++r) {
        int rloc = quad * 4 + r;
        TrA[rloc * 260 + w * 64 + tn * 16 + ln] = accA[tm][tn][r];
        TrB[rloc * 260 + w * 64 + tn * 16 + ln] = accB[tm][tn][r];
      }
    __syncthreads();
    const int i = i0 + tm * 16 + row;
#pragma unroll
    for (int u = 0; u < 4; ++u) {
      int c0 = (fq + u * 16) * 4;
      float4 a  = *(const float4*)(TrA + row * 260 + c0);
      float4 bm = *(const float4*)(TrB + row * 260 + c0);
      float4 c  = *(const float4*)(cxb + (size_t)i * DDD + c0);
      nt_store4(ob + (size_t)i * 1024 + 256 + c0, a.x, a.y, a.z, a.w);
      nt_store4(ob + (size_t)i * 1024 + 512 + c0, c.x*a.x, c.y*a.y, c.z*a.z, c.w*a.w);
      nt_store4(ob + (size_t)i * 1024 + 768 + c0, c.x*bm.x, c.y*bm.y, c.z*bm.z, c.w*bm.w);
    }
    __syncthreads();   // reads done before next park
  }
}

extern "C" void kernel_launch(void* const* d_in, const int* in_sizes, int n_in,
                              void* d_out, int out_size, void* d_ws, size_t ws_size,
                              hipStream_t stream) {
  const float* cx = (const float*)d_in[0];
  const float* qu = (const float*)d_in[1];
  const float* W  = (const float*)d_in[2];
  const float* Wb = (const float*)d_in[3];
  float* out = (float*)d_out;

  char* wsb = (char*)d_ws;
  unsigned short* P   = (unsigned short*)(wsb);                       // 4 MiB
  unsigned short* Et  = (unsigned short*)(wsb + (4ull << 20));        // 4 MiB
  unsigned short* Qt  = (unsigned short*)(wsb + (8ull << 20));        // 2 MiB
  unsigned short* Tt  = (unsigned short*)(wsb + (10ull << 20));       // 2 MiB
  float*          csp = (float*)(wsb + (12ull << 20));                // 128 KiB

  k1_scores<<<dim3(512), dim3(256), 0, stream>>>(cx, qu, W, Wb, P, Et, csp, out);
  k2_tmat  <<<dim3(512), dim3(256), 0, stream>>>(cx, qu, Et, csp, Qt, Tt);
  k3_out   <<<dim3(512), dim3(256), 0, stream>>>(cx, P, Qt, Tt, out);
}

// Round 2
// 200.498 us; speedup vs baseline: 1.0409x; 1.0409x over previous
//
#include <hip/hip_runtime.h>

#define BB 64
#define LCC 512
#define LQQ 64
#define DDD 256

typedef short bf16x8 __attribute__((ext_vector_type(8)));
typedef float f32x4 __attribute__((ext_vector_type(4)));

static __device__ __forceinline__ unsigned short f2bf(float f) {
  union { float f; unsigned u; } v; v.f = f;
  unsigned u = v.u;
  return (unsigned short)((u + 0x7fffu + ((u >> 16) & 1u)) >> 16);
}

static __device__ __forceinline__ void nt_store4(float* p, float a, float b, float c, float d) {
  f32x4 v = { a, b, c, d };
  __builtin_nontemporal_store(v, (f32x4*)p);
}

// ---------------------------------------------------------------------------
// Kernel 1: E = exp((cx*wi)@qu^T + s_c + s_q + bias); writes
//   P  = diag(1/rowsum) * E   (bf16, for k3's A and Bm)
//   Et = E^T                  (bf16, for k2's T)
//   csp[b][tile][64]          (f32 per-tile column-sum partials, for k2)
// Pure barrier-free MFMA K-loop (no out stores — that scatter cost ~15us).
// grid 512 = B x 8 LC-tiles of 64; 256 threads (4 waves).
// ---------------------------------------------------------------------------
__global__ __launch_bounds__(256) void k1_scores(
    const float* __restrict__ cx, const float* __restrict__ qu,
    const float* __restrict__ W, const float* __restrict__ Wb,
    unsigned short* __restrict__ P, unsigned short* __restrict__ Et,
    float* __restrict__ csp)
{
  __shared__ float w_lds[768];                 // wq | wc | wi
  __shared__ unsigned short Bs[64 * 264];      // qu tile bf16, full K, +8 pad
  __shared__ float E_lds[64 * 65];
  __shared__ float red[256];
  __shared__ float sc_lds[64];
  __shared__ float sq_lds[64];
  __shared__ float ri_s[64];

  const int tid = threadIdx.x;
  const int b    = blockIdx.x >> 3;
  const int tile = blockIdx.x & 7;
  const int i0 = tile * 64;
  const int w = tid >> 6, lane = tid & 63, quad = lane >> 4, ln = lane & 15;

  for (int idx = tid; idx < 768; idx += 256) w_lds[idx] = W[idx];
  __syncthreads();

  // stage Bs = qu (bf16, 64 x 256), fold s_q partials
  {
    const int bj = tid >> 2, bc = tid & 3;
    const float4* src = (const float4*)(qu + ((size_t)(b * LQQ + bj)) * DDD + bc * 64);
    const float* wq = w_lds + bc * 64;
    unsigned short* dst = Bs + bj * 264 + bc * 64;
    float sqp = 0.f;
#pragma unroll
    for (int u = 0; u < 16; ++u) {
      float4 v = src[u];
      sqp += v.x * wq[u*4+0] + v.y * wq[u*4+1] + v.z * wq[u*4+2] + v.w * wq[u*4+3];
      ushort4 o = { f2bf(v.x), f2bf(v.y), f2bf(v.z), f2bf(v.w) };
      *(ushort4*)(dst + u * 4) = o;
    }
    red[tid] = sqp;
  }
  __syncthreads();
  if (tid < 64) sq_lds[tid] = red[4*tid] + red[4*tid+1] + red[4*tid+2] + red[4*tid+3];

  f32x4 acc[4];
#pragma unroll
  for (int c = 0; c < 4; ++c) acc[c] = (f32x4){0.f, 0.f, 0.f, 0.f};

  // K loop: no barriers. A fragment = cx row (w*16+ln), k-slice quad*8.
  float scp = 0.f;
  const float* cxrow = cx + ((size_t)(b * LCC + i0 + w * 16 + ln)) * DDD;
#pragma unroll
  for (int kk = 0; kk < 4; ++kk)
#pragma unroll
    for (int ks = 0; ks < 2; ++ks) {
      const int k0 = kk * 64 + ks * 32 + quad * 8;
      float4 c0 = *(const float4*)(cxrow + k0);
      float4 c1 = *(const float4*)(cxrow + k0 + 4);
      const float* wcp = w_lds + 256 + k0;
      const float* wip = w_lds + 512 + k0;
      scp += c0.x*wcp[0] + c0.y*wcp[1] + c0.z*wcp[2] + c0.w*wcp[3]
           + c1.x*wcp[4] + c1.y*wcp[5] + c1.z*wcp[6] + c1.w*wcp[7];
      bf16x8 af;
      af[0] = (short)f2bf(c0.x * wip[0]);
      af[1] = (short)f2bf(c0.y * wip[1]);
      af[2] = (short)f2bf(c0.z * wip[2]);
      af[3] = (short)f2bf(c0.w * wip[3]);
      af[4] = (short)f2bf(c1.x * wip[4]);
      af[5] = (short)f2bf(c1.y * wip[5]);
      af[6] = (short)f2bf(c1.z * wip[6]);
      af[7] = (short)f2bf(c1.w * wip[7]);
#pragma unroll
      for (int tn = 0; tn < 4; ++tn) {
        bf16x8 bf = *(const bf16x8*)(Bs + (tn * 16 + ln) * 264 + k0);
        acc[tn] = __builtin_amdgcn_mfma_f32_16x16x32_bf16(af, bf, acc[tn], 0, 0, 0);
      }
    }

  // reduce s_c (4 quad-partials per row), add bias
  __syncthreads();
  red[(w * 16 + ln) * 4 + quad] = scp;
  __syncthreads();
  if (tid < 64)
    sc_lds[tid] = red[4*tid] + red[4*tid+1] + red[4*tid+2] + red[4*tid+3] + Wb[0];
  __syncthreads();

  // exp epilogue into E_lds (C/D layout: col=lane&15, row=quad*4+r)
#pragma unroll
  for (int tn = 0; tn < 4; ++tn)
#pragma unroll
    for (int r = 0; r < 4; ++r) {
      int il = w * 16 + quad * 4 + r;
      int j  = tn * 16 + ln;
      E_lds[il * 65 + j] = __expf(acc[tn][r] + sc_lds[il] + sq_lds[j]);
    }
  __syncthreads();
  // rowsum (4 threads/row) -> ri_s
  {
    const int i = tid >> 2, c = tid & 3;
    float s = 0.f;
#pragma unroll
    for (int j = 0; j < 16; ++j) s += E_lds[i * 65 + c * 16 + j];
    red[tid] = s;
  }
  __syncthreads();
  if (tid < 64)
    ri_s[tid] = 1.0f / (red[4*tid] + red[4*tid+1] + red[4*tid+2] + red[4*tid+3]);
  __syncthreads();
  // colsum partials (f32, unscaled E) -> csp
  {
    const int j = tid >> 2, c = tid & 3;
    float s = 0.f;
#pragma unroll
    for (int r = 0; r < 16; ++r) s += E_lds[(c * 16 + r) * 65 + j];
    red[tid] = s;
  }
  __syncthreads();
  if (tid < 64)
    csp[((size_t)(b * 8 + tile)) * 64 + tid] =
        red[4*tid] + red[4*tid+1] + red[4*tid+2] + red[4*tid+3];

  // write P = diag(1/rowsum)*E, natural (B, 512, 64) bf16
  {
    const int i = tid >> 2, c = tid & 3;
    const float ri = ri_s[i];
    unsigned short* dst = P + ((size_t)(b * LCC + i0 + i)) * 64 + c * 16;
    const float* srcr = E_lds + i * 65 + c * 16;
#pragma unroll
    for (int u = 0; u < 4; ++u) {
      ushort4 o = { f2bf(srcr[u*4+0]*ri), f2bf(srcr[u*4+1]*ri),
                    f2bf(srcr[u*4+2]*ri), f2bf(srcr[u*4+3]*ri) };
      *(ushort4*)(dst + u * 4) = o;
    }
  }
  // write E^T (B, 64, 512) bf16 (unscaled — k2 applies colsum scaling)
  {
    const int j = tid >> 2, c = tid & 3;
    unsigned short* dst = Et + ((size_t)(b * LQQ + j)) * LCC + i0 + c * 16;
#pragma unroll
    for (int u = 0; u < 4; ++u) {
      ushort4 o;
      o.x = f2bf(E_lds[(c*16 + u*4 + 0) * 65 + j]);
      o.y = f2bf(E_lds[(c*16 + u*4 + 1) * 65 + j]);
      o.z = f2bf(E_lds[(c*16 + u*4 + 2) * 65 + j]);
      o.w = f2bf(E_lds[(c*16 + u*4 + 3) * 65 + j]);
      *(ushort4*)(dst + u * 4) = o;
    }
  }
}

// ---------------------------------------------------------------------------
// Kernel 2: T = diag(1/colsum) * E^T @ contex -> T^T (bf16); also Q^T (bf16)
// colsum comes precomputed (f32 partials from k1). Staging loads remapped
// to 128B-contiguous per-row segments. grid 512 = B x 8 D-slices of 32.
// ---------------------------------------------------------------------------
__global__ __launch_bounds__(256) void k2_tmat(
    const float* __restrict__ cx, const float* __restrict__ qu,
    const unsigned short* __restrict__ Et, const float* __restrict__ csp,
    unsigned short* __restrict__ Qt, unsigned short* __restrict__ Tt)
{
  __shared__ unsigned short Bs2[32 * 72];
  __shared__ float Tl[64 * 37];
  __shared__ float csinv[64];

  const int tid = threadIdx.x;
  const int b  = blockIdx.x >> 3;
  const int d0 = (blockIdx.x & 7) * 32;
  const int w = tid >> 6, lane = tid & 63, quad = lane >> 4, ln = lane & 15;

  // ---- transpose question slice -> Qt ----
  {
    const int j = tid >> 2, c = tid & 3;
    const float* srow = qu + ((size_t)(b * LQQ + j)) * DDD + d0 + c * 8;
    float4 v0 = *(const float4*)srow;
    float4 v1 = *(const float4*)(srow + 4);
    float* t = Tl + j * 37 + c * 8;
    t[0]=v0.x; t[1]=v0.y; t[2]=v0.z; t[3]=v0.w;
    t[4]=v1.x; t[5]=v1.y; t[6]=v1.z; t[7]=v1.w;
  }
  __syncthreads();
  {
    const int d = tid >> 3, cj = tid & 7;
    unsigned short* dst = Qt + ((size_t)(b * DDD + d0 + d)) * 64 + cj * 8;
    ushort4 o0 = { f2bf(Tl[(cj*8+0)*37+d]), f2bf(Tl[(cj*8+1)*37+d]),
                   f2bf(Tl[(cj*8+2)*37+d]), f2bf(Tl[(cj*8+3)*37+d]) };
    ushort4 o1 = { f2bf(Tl[(cj*8+4)*37+d]), f2bf(Tl[(cj*8+5)*37+d]),
                   f2bf(Tl[(cj*8+6)*37+d]), f2bf(Tl[(cj*8+7)*37+d]) };
    *(ushort4*)dst = o0;
    *(ushort4*)(dst + 4) = o1;
  }

  // exact colsum inverse from k1's f32 partials
  if (tid < 64) {
    float s = 0.f;
#pragma unroll
    for (int t = 0; t < 8; ++t) s += csp[((size_t)(b * 8 + t)) * 64 + tid];
    csinv[tid] = 1.0f / s;
  }

  f32x4 acc[2];
  acc[0] = (f32x4){0.f, 0.f, 0.f, 0.f};
  acc[1] = (f32x4){0.f, 0.f, 0.f, 0.f};
  const unsigned short* etrow = Et + ((size_t)(b * LQQ + w * 16 + ln)) * LCC;
  const int r2 = tid >> 2, c2 = tid & 3;

  for (int kk = 0; kk < 8; ++kk) {
    __syncthreads();   // previous Bs2 reads done (also fences Qt-phase Tl reads at kk=0)
    // stage Bs2[d][i] = contex[k0+i][d0+d] (bf16 transposed)
    // thread owns row r2, 8-col chunk c2 -> 128B contiguous loads per row
    {
      const float* srow = cx + ((size_t)(b * LCC + kk * 64 + r2)) * DDD + d0 + c2 * 8;
      float4 v0 = *(const float4*)srow;
      float4 v1 = *(const float4*)(srow + 4);
      Bs2[(c2*8+0)*72 + r2] = f2bf(v0.x);
      Bs2[(c2*8+1)*72 + r2] = f2bf(v0.y);
      Bs2[(c2*8+2)*72 + r2] = f2bf(v0.z);
      Bs2[(c2*8+3)*72 + r2] = f2bf(v0.w);
      Bs2[(c2*8+4)*72 + r2] = f2bf(v1.x);
      Bs2[(c2*8+5)*72 + r2] = f2bf(v1.y);
      Bs2[(c2*8+6)*72 + r2] = f2bf(v1.z);
      Bs2[(c2*8+7)*72 + r2] = f2bf(v1.w);
    }
    // direct-global A fragments
    bf16x8 af0 = *(const bf16x8*)(etrow + kk * 64 + quad * 8);
    bf16x8 af1 = *(const bf16x8*)(etrow + kk * 64 + 32 + quad * 8);
    __syncthreads();
#pragma unroll
    for (int tn = 0; tn < 2; ++tn) {
      bf16x8 bf0 = *(const bf16x8*)(Bs2 + (tn * 16 + ln) * 72 + quad * 8);
      bf16x8 bf1 = *(const bf16x8*)(Bs2 + (tn * 16 + ln) * 72 + 32 + quad * 8);
      acc[tn] = __builtin_amdgcn_mfma_f32_16x16x32_bf16(af0, bf0, acc[tn], 0, 0, 0);
      acc[tn] = __builtin_amdgcn_mfma_f32_16x16x32_bf16(af1, bf1, acc[tn], 0, 0, 0);
    }
  }

  // park T (scaled) into Tl
#pragma unroll
  for (int tn = 0; tn < 2; ++tn)
#pragma unroll
    for (int r = 0; r < 4; ++r) {
      int j = w * 16 + quad * 4 + r;
      Tl[j * 37 + tn * 16 + ln] = acc[tn][r] * csinv[j];
    }
  __syncthreads();
  // write T^T (B, 256, 64) bf16
  {
    const int d = tid >> 3, cj = tid & 7;
    unsigned short* dst = Tt + ((size_t)(b * DDD + d0 + d)) * 64 + cj * 8;
    ushort4 o0 = { f2bf(Tl[(cj*8+0)*37+d]), f2bf(Tl[(cj*8+1)*37+d]),
                   f2bf(Tl[(cj*8+2)*37+d]), f2bf(Tl[(cj*8+3)*37+d]) };
    ushort4 o1 = { f2bf(Tl[(cj*8+4)*37+d]), f2bf(Tl[(cj*8+5)*37+d]),
                   f2bf(Tl[(cj*8+6)*37+d]), f2bf(Tl[(cj*8+7)*37+d]) };
    *(ushort4*)dst = o0;
    *(ushort4*)(dst + 4) = o1;
  }
}

// ---------------------------------------------------------------------------
// Kernel 3: A = P @ qu, Bm = P @ T  (P already rowsum-scaled). One block per
// 64-row tile computes BOTH products; reads P and cx once; writes all four
// output chunks [cx | A | cx*A | cx*Bm] fully coalesced. grid 512 = B x 8.
// ---------------------------------------------------------------------------
__global__ __launch_bounds__(256, 2) void k3_out(
    const float* __restrict__ cx,
    const unsigned short* __restrict__ P,
    const unsigned short* __restrict__ Qt,
    const unsigned short* __restrict__ Tt,
    float* __restrict__ out)
{
  __shared__ float TrA[16 * 260];
  __shared__ float TrB[16 * 260];

  const int tid = threadIdx.x;
  const int b  = blockIdx.x >> 3;
  const int i0 = (blockIdx.x & 7) * 64;
  const int w = tid >> 6, lane = tid & 63, quad = lane >> 4, ln = lane & 15;

  const unsigned short* pbase = P + ((size_t)(b * LCC + i0)) * 64;
  const unsigned short* qbase = Qt + (size_t)b * DDD * 64;
  const unsigned short* tbase = Tt + (size_t)b * DDD * 64;

  f32x4 accA[4][4], accB[4][4];
#pragma unroll
  for (int a = 0; a < 4; ++a)
#pragma unroll
    for (int c = 0; c < 4; ++c) {
      accA[a][c] = (f32x4){0.f, 0.f, 0.f, 0.f};
      accB[a][c] = (f32x4){0.f, 0.f, 0.f, 0.f};
    }

#pragma unroll
  for (int ks = 0; ks < 2; ++ks) {
    bf16x8 af[4];
#pragma unroll
    for (int tm = 0; tm < 4; ++tm)
      af[tm] = *(const bf16x8*)(pbase + (tm * 16 + ln) * 64 + ks * 32 + quad * 8);
#pragma unroll
    for (int tn = 0; tn < 4; ++tn) {
      const size_t boff = ((size_t)(w * 64 + tn * 16 + ln)) * 64 + ks * 32 + quad * 8;
      bf16x8 bq = *(const bf16x8*)(qbase + boff);
      bf16x8 bt = *(const bf16x8*)(tbase + boff);
#pragma unroll
      for (int tm = 0; tm < 4; ++tm) {
        accA[tm][tn] = __builtin_amdgcn_mfma_f32_16x16x32_bf16(af[tm], bq, accA[tm][tn], 0, 0, 0);
        accB[tm][tn] = __builtin_amdgcn_mfma_f32_16x16x32_bf16(af[tm], bt, accB[tm][tn], 0, 0, 0);
      }
    }
  }

  const float* cxb = cx + (size_t)b * LCC * DDD;
  float* ob = out + (size_t)b * LCC * 1024;
  const int row = tid >> 4;   // 0..15
  const int fq  = tid & 15;

#pragma unroll
  for (int tm = 0; tm < 4; ++tm) {
    // park 16 rows x 256 cols of A and Bm (C/D-layout -> row-major)
#pragma unroll
    for (int tn = 0; tn < 4; ++tn)
#pragma unroll
      for (int r = 0; r < 4; ++r) {
        int rloc = quad * 4 + r;
        TrA[rloc * 260 + w * 64 + tn * 16 + ln] = accA[tm][tn][r];
        TrB[rloc * 260 + w * 64 + tn * 16 + ln] = accB[tm][tn][r];
      }
    __syncthreads();
    const int i = i0 + tm * 16 + row;
#pragma unroll
    for (int u = 0; u < 4; ++u) {
      int c0 = (fq + u * 16) * 4;
      float4 a  = *(const float4*)(TrA + row * 260 + c0);
      float4 bm = *(const float4*)(TrB + row * 260 + c0);
      float4 c  = *(const float4*)(cxb + (size_t)i * DDD + c0);
      nt_store4(ob + (size_t)i * 1024 + c0,       c.x, c.y, c.z, c.w);
      nt_store4(ob + (size_t)i * 1024 + 256 + c0, a.x, a.y, a.z, a.w);
      nt_store4(ob + (size_t)i * 1024 + 512 + c0, c.x*a.x, c.y*a.y, c.z*a.z, c.w*a.w);
      nt_store4(ob + (size_t)i * 1024 + 768 + c0, c.x*bm.x, c.y*bm.y, c.z*bm.z, c.w*bm.w);
    }
    __syncthreads();   // reads done before next park
  }
}

extern "C" void kernel_launch(void* const* d_in, const int* in_sizes, int n_in,
                              void* d_out, int out_size, void* d_ws, size_t ws_size,
                              hipStream_t stream) {
  const float* cx = (const float*)d_in[0];
  const float* qu = (const float*)d_in[1];
  const float* W  = (const float*)d_in[2];
  const float* Wb = (const float*)d_in[3];
  float* out = (float*)d_out;

  char* wsb = (char*)d_ws;
  unsigned short* P   = (unsigned short*)(wsb);                       // 4 MiB
  unsigned short* Et  = (unsigned short*)(wsb + (4ull << 20));        // 4 MiB
  unsigned short* Qt  = (unsigned short*)(wsb + (8ull << 20));        // 2 MiB
  unsigned short* Tt  = (unsigned short*)(wsb + (10ull << 20));       // 2 MiB
  float*          csp = (float*)(wsb + (12ull << 20));                // 128 KiB

  k1_scores<<<dim3(512), dim3(256), 0, stream>>>(cx, qu, W, Wb, P, Et, csp);
  k2_tmat  <<<dim3(512), dim3(256), 0, stream>>>(cx, qu, Et, csp, Qt, Tt);
  k3_out   <<<dim3(512), dim3(256), 0, stream>>>(cx, P, Qt, Tt, out);
}

// Round 4
// 198.107 us; speedup vs baseline: 1.0534x; 1.0121x over previous
//
#include <hip/hip_runtime.h>
#include <hip/hip_bf16.h>

#define BB 64
#define LCC 512
#define LQQ 64
#define DDD 256

typedef short bf16x8 __attribute__((ext_vector_type(8)));
typedef float f32x4 __attribute__((ext_vector_type(4)));
typedef unsigned u32x4 __attribute__((ext_vector_type(4)));

// HW packed conversion: 2 floats -> 2 bf16 in one v_cvt_pk_bf16_f32 (gfx950).
static __device__ __forceinline__ unsigned pk2bf(float a, float b) {
  __hip_bfloat162 h = __float22bfloat162_rn(make_float2(a, b));
  unsigned u;
  __builtin_memcpy(&u, &h, sizeof(u));
  return u;
}
static __device__ __forceinline__ unsigned short bf1(float f) {
  __hip_bfloat16 h = __float2bfloat16(f);
  unsigned short u;
  __builtin_memcpy(&u, &h, sizeof(u));
  return u;
}

static __device__ __forceinline__ void nt_store4(float* p, float a, float b, float c, float d) {
  f32x4 v = { a, b, c, d };
  __builtin_nontemporal_store(v, (f32x4*)p);
}

// ---------------------------------------------------------------------------
// Kernel 1: E = exp((cx*wi)@qu^T + s_c + s_q + bias); writes
//   P  = diag(1/rowsum) * E   (bf16)
//   Et = E^T                  (bf16, unscaled)
//   csp[b][tile][64]          (f32 per-tile column-sum partials)
// HW cvt_pk for all f32->bf16; shuffle reductions (no red[] LDS, 4 barriers).
// grid 512 = B x 8 LC-tiles of 64; 256 threads (4 waves).
// ---------------------------------------------------------------------------
__global__ __launch_bounds__(256) void k1_scores(
    const float* __restrict__ cx, const float* __restrict__ qu,
    const float* __restrict__ W, const float* __restrict__ Wb,
    unsigned short* __restrict__ P, unsigned short* __restrict__ Et,
    float* __restrict__ csp)
{
  __shared__ float w_lds[768];                 // wq | wc | wi
  __shared__ unsigned short Bs[64 * 264];      // qu tile bf16, full K, +8 pad
  __shared__ float E_lds[64 * 65];
  __shared__ float sc_lds[64];
  __shared__ float sq_lds[64];

  const int tid = threadIdx.x;
  const int b    = blockIdx.x >> 3;
  const int tile = blockIdx.x & 7;
  const int i0 = tile * 64;
  const int w = tid >> 6, lane = tid & 63, quad = lane >> 4, ln = lane & 15;

  for (int idx = tid; idx < 768; idx += 256) w_lds[idx] = W[idx];
  __syncthreads();

  // stage Bs = qu (bf16, 64 x 256), fold s_q partials (shfl-reduced)
  {
    const int bj = tid >> 2, bc = tid & 3;
    const float4* src = (const float4*)(qu + ((size_t)(b * LQQ + bj)) * DDD + bc * 64);
    const float* wq = w_lds + bc * 64;
    unsigned short* dst = Bs + bj * 264 + bc * 64;
    float sqp = 0.f;
#pragma unroll
    for (int u = 0; u < 16; ++u) {
      float4 v = src[u];
      sqp += v.x * wq[u*4+0] + v.y * wq[u*4+1] + v.z * wq[u*4+2] + v.w * wq[u*4+3];
      uint2 o = { pk2bf(v.x, v.y), pk2bf(v.z, v.w) };
      *(uint2*)(dst + u * 4) = o;
    }
    sqp += __shfl_xor(sqp, 1);
    sqp += __shfl_xor(sqp, 2);
    if ((tid & 3) == 0) sq_lds[bj] = sqp;
  }
  __syncthreads();

  f32x4 acc[4];
#pragma unroll
  for (int c = 0; c < 4; ++c) acc[c] = (f32x4){0.f, 0.f, 0.f, 0.f};

  // K loop: no barriers. A fragment = cx row (w*16+ln), k-slice quad*8.
  float scp = 0.f;
  const float* cxrow = cx + ((size_t)(b * LCC + i0 + w * 16 + ln)) * DDD;
#pragma unroll
  for (int kk = 0; kk < 4; ++kk)
#pragma unroll
    for (int ks = 0; ks < 2; ++ks) {
      const int k0 = kk * 64 + ks * 32 + quad * 8;
      float4 c0 = *(const float4*)(cxrow + k0);
      float4 c1 = *(const float4*)(cxrow + k0 + 4);
      const float* wcp = w_lds + 256 + k0;
      const float* wip = w_lds + 512 + k0;
      scp += c0.x*wcp[0] + c0.y*wcp[1] + c0.z*wcp[2] + c0.w*wcp[3]
           + c1.x*wcp[4] + c1.y*wcp[5] + c1.z*wcp[6] + c1.w*wcp[7];
      u32x4 av = { pk2bf(c0.x * wip[0], c0.y * wip[1]),
                   pk2bf(c0.z * wip[2], c0.w * wip[3]),
                   pk2bf(c1.x * wip[4], c1.y * wip[5]),
                   pk2bf(c1.z * wip[6], c1.w * wip[7]) };
      bf16x8 af;
      __builtin_memcpy(&af, &av, sizeof(af));
#pragma unroll
      for (int tn = 0; tn < 4; ++tn) {
        bf16x8 bf = *(const bf16x8*)(Bs + (tn * 16 + ln) * 264 + k0);
        acc[tn] = __builtin_amdgcn_mfma_f32_16x16x32_bf16(af, bf, acc[tn], 0, 0, 0);
      }
    }

  // reduce s_c across quads (shfl butterfly over lane bits 4,5), add bias
  scp += __shfl_xor(scp, 16);
  scp += __shfl_xor(scp, 32);
  if (lane < 16) sc_lds[w * 16 + ln] = scp + Wb[0];
  __syncthreads();

  // exp epilogue into E_lds (C/D layout: col=lane&15, row=quad*4+r)
#pragma unroll
  for (int tn = 0; tn < 4; ++tn)
#pragma unroll
    for (int r = 0; r < 4; ++r) {
      int il = w * 16 + quad * 4 + r;
      int j  = tn * 16 + ln;
      E_lds[il * 65 + j] = __expf(acc[tn][r] + sc_lds[il] + sq_lds[j]);
    }
  __syncthreads();

  // rowsum (4 threads/row, shfl-combined) -> P = diag(1/rowsum)*E directly
  {
    const int i = tid >> 2, c = tid & 3;
    const float* srcr = E_lds + i * 65 + c * 16;
    float s = 0.f;
#pragma unroll
    for (int j = 0; j < 16; ++j) s += srcr[j];
    s += __shfl_xor(s, 1);
    s += __shfl_xor(s, 2);
    const float ri = 1.0f / s;
    unsigned short* dst = P + ((size_t)(b * LCC + i0 + i)) * 64 + c * 16;
#pragma unroll
    for (int u = 0; u < 4; ++u) {
      uint2 o = { pk2bf(srcr[u*4+0]*ri, srcr[u*4+1]*ri),
                  pk2bf(srcr[u*4+2]*ri, srcr[u*4+3]*ri) };
      *(uint2*)(dst + u * 4) = o;
    }
  }
  // colsum partials (f32, unscaled E) -> csp (shfl-combined)
  {
    const int j = tid >> 2, c = tid & 3;
    float s = 0.f;
#pragma unroll
    for (int r = 0; r < 16; ++r) s += E_lds[(c * 16 + r) * 65 + j];
    s += __shfl_xor(s, 1);
    s += __shfl_xor(s, 2);
    if ((tid & 3) == 0) csp[((size_t)(b * 8 + tile)) * 64 + j] = s;
  }
  // write E^T (B, 64, 512) bf16 (unscaled — k2 applies colsum scaling)
  {
    const int j = tid >> 2, c = tid & 3;
    unsigned short* dst = Et + ((size_t)(b * LQQ + j)) * LCC + i0 + c * 16;
#pragma unroll
    for (int u = 0; u < 4; ++u) {
      uint2 o = { pk2bf(E_lds[(c*16 + u*4 + 0) * 65 + j],
                        E_lds[(c*16 + u*4 + 1) * 65 + j]),
                  pk2bf(E_lds[(c*16 + u*4 + 2) * 65 + j],
                        E_lds[(c*16 + u*4 + 3) * 65 + j]) };
      *(uint2*)(dst + u * 4) = o;
    }
  }
}

// ---------------------------------------------------------------------------
// Kernel 2: T = diag(1/colsum) * E^T @ contex -> T^T (bf16); also Q^T (bf16)
// Double-buffered staging (1 barrier/iter); HW cvt for bf16 packing.
// grid 512 = B x 8 D-slices of 32; 256 threads (4 waves).
// ---------------------------------------------------------------------------
__global__ __launch_bounds__(256) void k2_tmat(
    const float* __restrict__ cx, const float* __restrict__ qu,
    const unsigned short* __restrict__ Et, const float* __restrict__ csp,
    unsigned short* __restrict__ Qt, unsigned short* __restrict__ Tt)
{
  __shared__ unsigned short Bs2[2][32 * 72];
  __shared__ float Tl[64 * 37];
  __shared__ float csinv[64];

  const int tid = threadIdx.x;
  const int b  = blockIdx.x >> 3;
  const int d0 = (blockIdx.x & 7) * 32;
  const int w = tid >> 6, lane = tid & 63, quad = lane >> 4, ln = lane & 15;

  // ---- transpose question slice -> Qt ----
  {
    const int j = tid >> 2, c = tid & 3;
    const float* srow = qu + ((size_t)(b * LQQ + j)) * DDD + d0 + c * 8;
    float4 v0 = *(const float4*)srow;
    float4 v1 = *(const float4*)(srow + 4);
    float* t = Tl + j * 37 + c * 8;
    t[0]=v0.x; t[1]=v0.y; t[2]=v0.z; t[3]=v0.w;
    t[4]=v1.x; t[5]=v1.y; t[6]=v1.z; t[7]=v1.w;
  }
  // exact colsum inverse from k1's f32 partials
  if (tid < 64) {
    float s = 0.f;
#pragma unroll
    for (int t = 0; t < 8; ++t) s += csp[((size_t)(b * 8 + t)) * 64 + tid];
    csinv[tid] = 1.0f / s;
  }
  __syncthreads();
  {
    const int d = tid >> 3, cj = tid & 7;
    unsigned short* dst = Qt + ((size_t)(b * DDD + d0 + d)) * 64 + cj * 8;
    uint2 o0 = { pk2bf(Tl[(cj*8+0)*37+d], Tl[(cj*8+1)*37+d]),
                 pk2bf(Tl[(cj*8+2)*37+d], Tl[(cj*8+3)*37+d]) };
    uint2 o1 = { pk2bf(Tl[(cj*8+4)*37+d], Tl[(cj*8+5)*37+d]),
                 pk2bf(Tl[(cj*8+6)*37+d], Tl[(cj*8+7)*37+d]) };
    *(uint2*)dst = o0;
    *(uint2*)(dst + 4) = o1;
  }

  f32x4 acc[2];
  acc[0] = (f32x4){0.f, 0.f, 0.f, 0.f};
  acc[1] = (f32x4){0.f, 0.f, 0.f, 0.f};
  const unsigned short* etrow = Et + ((size_t)(b * LQQ + w * 16 + ln)) * LCC;
  const int r2 = tid >> 2, c2 = tid & 3;

  for (int kk = 0; kk < 8; ++kk) {
    unsigned short* bufw = Bs2[kk & 1];
    // stage Bs2[d][i] = contex[k0+i][d0+d] (bf16 transposed)
    // thread owns row r2, 8-col chunk c2 -> 128B contiguous loads per row
    {
      const float* srow = cx + ((size_t)(b * LCC + kk * 64 + r2)) * DDD + d0 + c2 * 8;
      float4 v0 = *(const float4*)srow;
      float4 v1 = *(const float4*)(srow + 4);
      bufw[(c2*8+0)*72 + r2] = bf1(v0.x);
      bufw[(c2*8+1)*72 + r2] = bf1(v0.y);
      bufw[(c2*8+2)*72 + r2] = bf1(v0.z);
      bufw[(c2*8+3)*72 + r2] = bf1(v0.w);
      bufw[(c2*8+4)*72 + r2] = bf1(v1.x);
      bufw[(c2*8+5)*72 + r2] = bf1(v1.y);
      bufw[(c2*8+6)*72 + r2] = bf1(v1.z);
      bufw[(c2*8+7)*72 + r2] = bf1(v1.w);
    }
    // direct-global A fragments
    bf16x8 af0 = *(const bf16x8*)(etrow + kk * 64 + quad * 8);
    bf16x8 af1 = *(const bf16x8*)(etrow + kk * 64 + 32 + quad * 8);
    __syncthreads();
    const unsigned short* bufr = Bs2[kk & 1];
#pragma unroll
    for (int tn = 0; tn < 2; ++tn) {
      bf16x8 bf0 = *(const bf16x8*)(bufr + (tn * 16 + ln) * 72 + quad * 8);
      bf16x8 bf1v = *(const bf16x8*)(bufr + (tn * 16 + ln) * 72 + 32 + quad * 8);
      acc[tn] = __builtin_amdgcn_mfma_f32_16x16x32_bf16(af0, bf0, acc[tn], 0, 0, 0);
      acc[tn] = __builtin_amdgcn_mfma_f32_16x16x32_bf16(af1, bf1v, acc[tn], 0, 0, 0);
    }
  }

  // park T (scaled) into Tl
#pragma unroll
  for (int tn = 0; tn < 2; ++tn)
#pragma unroll
    for (int r = 0; r < 4; ++r) {
      int j = w * 16 + quad * 4 + r;
      Tl[j * 37 + tn * 16 + ln] = acc[tn][r] * csinv[j];
    }
  __syncthreads();
  // write T^T (B, 256, 64) bf16
  {
    const int d = tid >> 3, cj = tid & 7;
    unsigned short* dst = Tt + ((size_t)(b * DDD + d0 + d)) * 64 + cj * 8;
    uint2 o0 = { pk2bf(Tl[(cj*8+0)*37+d], Tl[(cj*8+1)*37+d]),
                 pk2bf(Tl[(cj*8+2)*37+d], Tl[(cj*8+3)*37+d]) };
    uint2 o1 = { pk2bf(Tl[(cj*8+4)*37+d], Tl[(cj*8+5)*37+d]),
                 pk2bf(Tl[(cj*8+6)*37+d], Tl[(cj*8+7)*37+d]) };
    *(uint2*)dst = o0;
    *(uint2*)(dst + 4) = o1;
  }
}

// ---------------------------------------------------------------------------
// Kernel 3: A = P @ qu, Bm = P @ T  (P already rowsum-scaled). One block per
// 64-row tile computes BOTH products; reads P and cx once; writes all four
// output chunks [cx | A | cx*A | cx*Bm] fully coalesced. grid 512 = B x 8.
// ---------------------------------------------------------------------------
__global__ __launch_bounds__(256, 2) void k3_out(
    const float* __restrict__ cx,
    const unsigned short* __restrict__ P,
    const unsigned short* __restrict__ Qt,
    const unsigned short* __restrict__ Tt,
    float* __restrict__ out)
{
  __shared__ float TrA[16 * 260];
  __shared__ float TrB[16 * 260];

  const int tid = threadIdx.x;
  const int b  = blockIdx.x >> 3;
  const int i0 = (blockIdx.x & 7) * 64;
  const int w = tid >> 6, lane = tid & 63, quad = lane >> 4, ln = lane & 15;

  const unsigned short* pbase = P + ((size_t)(b * LCC + i0)) * 64;
  const unsigned short* qbase = Qt + (size_t)b * DDD * 64;
  const unsigned short* tbase = Tt + (size_t)b * DDD * 64;

  f32x4 accA[4][4], accB[4][4];
#pragma unroll
  for (int a = 0; a < 4; ++a)
#pragma unroll
    for (int c = 0; c < 4; ++c) {
      accA[a][c] = (f32x4){0.f, 0.f, 0.f, 0.f};
      accB[a][c] = (f32x4){0.f, 0.f, 0.f, 0.f};
    }

#pragma unroll
  for (int ks = 0; ks < 2; ++ks) {
    bf16x8 af[4];
#pragma unroll
    for (int tm = 0; tm < 4; ++tm)
      af[tm] = *(const bf16x8*)(pbase + (tm * 16 + ln) * 64 + ks * 32 + quad * 8);
#pragma unroll
    for (int tn = 0; tn < 4; ++tn) {
      const size_t boff = ((size_t)(w * 64 + tn * 16 + ln)) * 64 + ks * 32 + quad * 8;
      bf16x8 bq = *(const bf16x8*)(qbase + boff);
      bf16x8 bt = *(const bf16x8*)(tbase + boff);
#pragma unroll
      for (int tm = 0; tm < 4; ++tm) {
        accA[tm][tn] = __builtin_amdgcn_mfma_f32_16x16x32_bf16(af[tm], bq, accA[tm][tn], 0, 0, 0);
        accB[tm][tn] = __builtin_amdgcn_mfma_f32_16x16x32_bf16(af[tm], bt, accB[tm][tn], 0, 0, 0);
      }
    }
  }

  const float* cxb = cx + (size_t)b * LCC * DDD;
  float* ob = out + (size_t)b * LCC * 1024;
  const int row = tid >> 4;   // 0..15
  const int fq  = tid & 15;

#pragma unroll
  for (int tm = 0; tm < 4; ++tm) {
    // park 16 rows x 256 cols of A and Bm (C/D-layout -> row-major)
#pragma unroll
    for (int tn = 0; tn < 4; ++tn)
#pragma unroll
      for (int r = 0; r < 4; ++r) {
        int rloc = quad * 4 + r;
        TrA[rloc * 260 + w * 64 + tn * 16 + ln] = accA[tm][tn][r];
        TrB[rloc * 260 + w * 64 + tn * 16 + ln] = accB[tm][tn][r];
      }
    __syncthreads();
    const int i = i0 + tm * 16 + row;
#pragma unroll
    for (int u = 0; u < 4; ++u) {
      int c0 = (fq + u * 16) * 4;
      float4 a  = *(const float4*)(TrA + row * 260 + c0);
      float4 bm = *(const float4*)(TrB + row * 260 + c0);
      float4 c  = *(const float4*)(cxb + (size_t)i * DDD + c0);
      nt_store4(ob + (size_t)i * 1024 + c0,       c.x, c.y, c.z, c.w);
      nt_store4(ob + (size_t)i * 1024 + 256 + c0, a.x, a.y, a.z, a.w);
      nt_store4(ob + (size_t)i * 1024 + 512 + c0, c.x*a.x, c.y*a.y, c.z*a.z, c.w*a.w);
      nt_store4(ob + (size_t)i * 1024 + 768 + c0, c.x*bm.x, c.y*bm.y, c.z*bm.z, c.w*bm.w);
    }
    __syncthreads();   // reads done before next park
  }
}

extern "C" void kernel_launch(void* const* d_in, const int* in_sizes, int n_in,
                              void* d_out, int out_size, void* d_ws, size_t ws_size,
                              hipStream_t stream) {
  const float* cx = (const float*)d_in[0];
  const float* qu = (const float*)d_in[1];
  const float* W  = (const float*)d_in[2];
  const float* Wb = (const float*)d_in[3];
  float* out = (float*)d_out;

  char* wsb = (char*)d_ws;
  unsigned short* P   = (unsigned short*)(wsb);                       // 4 MiB
  unsigned short* Et  = (unsigned short*)(wsb + (4ull << 20));        // 4 MiB
  unsigned short* Qt  = (unsigned short*)(wsb + (8ull << 20));        // 2 MiB
  unsigned short* Tt  = (unsigned short*)(wsb + (10ull << 20));       // 2 MiB
  float*          csp = (float*)(wsb + (12ull << 20));                // 128 KiB

  k1_scores<<<dim3(512), dim3(256), 0, stream>>>(cx, qu, W, Wb, P, Et, csp);
  k2_tmat  <<<dim3(512), dim3(256), 0, stream>>>(cx, qu, Et, csp, Qt, Tt);
  k3_out   <<<dim3(512), dim3(256), 0, stream>>>(cx, P, Qt, Tt, out);
}